// Round 2
// baseline (777.215 us; speedup 1.0000x reference)
//
#include <hip/hip_runtime.h>

// Problem constants (SelfAttention_Pseudoformer): B=8, L=2048, C=512, P=64, H=8, DK=64
// Outputs (concatenated, FLOAT32): z [B,L,C], pScore(masked) [B,L,P], scores [B,H,L,P]

// ---------------------------------------------------------------------------
// Generic tiled f32 GEMM: C = A[M,K] @ B[K,N] (+bias), row-major, f32 out.
// Requires M%64==0, N%64==0, K%16==0 (true for all shapes here).
// Batched via blockIdx.z with strides sA/sB/sC.
// ---------------------------------------------------------------------------
__global__ __launch_bounds__(256)
void gemm_f32(const float* __restrict__ A, const float* __restrict__ Bm,
              const float* __restrict__ bias, float* __restrict__ C,
              int M, int N, int K, long sA, long sB, long sC)
{
  __shared__ float As[16][68];   // [k][row], padded
  __shared__ float Bs[16][64];   // [k][col]
  const int bz = blockIdx.z;
  A  += (long)bz * sA;
  Bm += (long)bz * sB;
  C  += (long)bz * sC;
  const int row0 = blockIdx.y * 64, col0 = blockIdx.x * 64;
  const int tid = threadIdx.x;
  const int tx = tid & 15, ty = tid >> 4;
  const int ar = tid >> 2, ak = (tid & 3) << 2;   // A: row ar, k-offset ak (4 wide)
  const int bkr = tid >> 4, bc = (tid & 15) << 2; // B: k-row bkr, col bc (4 wide)
  float acc[4][4] = {};
  for (int k0 = 0; k0 < K; k0 += 16) {
    float4 a4 = *(const float4*)(A + (long)(row0 + ar) * K + k0 + ak);
    As[ak + 0][ar] = a4.x; As[ak + 1][ar] = a4.y;
    As[ak + 2][ar] = a4.z; As[ak + 3][ar] = a4.w;
    *(float4*)(&Bs[bkr][bc]) = *(const float4*)(Bm + (long)(k0 + bkr) * N + col0 + bc);
    __syncthreads();
#pragma unroll
    for (int kk = 0; kk < 16; ++kk) {
      float4 av = *(const float4*)(&As[kk][ty * 4]);
      float4 bv = *(const float4*)(&Bs[kk][tx * 4]);
      float a[4] = {av.x, av.y, av.z, av.w};
      float b[4] = {bv.x, bv.y, bv.z, bv.w};
#pragma unroll
      for (int i = 0; i < 4; ++i)
#pragma unroll
        for (int j = 0; j < 4; ++j) acc[i][j] += a[i] * b[j];
    }
    __syncthreads();
  }
  float4 bv4 = make_float4(0.f, 0.f, 0.f, 0.f);
  if (bias) bv4 = *(const float4*)(bias + col0 + tx * 4);
#pragma unroll
  for (int i = 0; i < 4; ++i) {
    long r = row0 + ty * 4 + i;
    *(float4*)(C + r * N + col0 + tx * 4) =
        make_float4(acc[i][0] + bv4.x, acc[i][1] + bv4.y,
                    acc[i][2] + bv4.z, acc[i][3] + bv4.w);
  }
}

// ---------------------------------------------------------------------------
// Mask + softmax over L (per (b,p) column) + normalized inclusive prefix scan.
// Reads f32 pScore, writes masked pScore (f32) to d_out, pAlphaT [B,P,L] and
// PS [B,P,L] (inclusive prefix of normalized pAlpha) to workspace.
// ---------------------------------------------------------------------------
__global__ __launch_bounds__(256)
void softmax_scan(const float* __restrict__ pscF, const int* __restrict__ maskPAD,
                  float* __restrict__ ps_out,
                  float* __restrict__ pAlphaT, float* __restrict__ PS)
{
  const int L = 2048, P = 64;
  __shared__ float red[256];
  const int p = blockIdx.x, b = blockIdx.y, t = threadIdx.x;
  const float* col = pscF + (size_t)b * L * P + p;
  float* ocol = ps_out + (size_t)b * L * P + p;
  const int* mrow = maskPAD + (size_t)b * L * L;   // maskPAD[b, 0, :]
  float v[8]; float mx = -3.4e38f;
#pragma unroll
  for (int i = 0; i < 8; ++i) {
    int l = t * 8 + i;
    float x = col[(size_t)l * P];
    if (mrow[l] == 0) x = -32768.0f;                // -2^15
    v[i] = x; mx = fmaxf(mx, x);
    ocol[(size_t)l * P] = x;                        // masked pScore output (f32)
  }
  red[t] = mx; __syncthreads();
  for (int s = 128; s > 0; s >>= 1) {
    if (t < s) red[t] = fmaxf(red[t], red[t + s]);
    __syncthreads();
  }
  float m = red[0]; __syncthreads();
  float e[8]; float s = 0.f;
#pragma unroll
  for (int i = 0; i < 8; ++i) { e[i] = expf(v[i] - m); s += e[i]; }
  red[t] = s; __syncthreads();
  for (int o = 1; o < 256; o <<= 1) {               // Hillis-Steele inclusive scan
    float x = (t >= o) ? red[t - o] : 0.f;
    __syncthreads();
    red[t] += x;
    __syncthreads();
  }
  float T = red[255];
  float excl = red[t] - s;
  float inv = 1.0f / T;
  float run = excl;
  size_t base = ((size_t)b * P + p) * L + (size_t)t * 8;
#pragma unroll
  for (int i = 0; i < 8; ++i) {
    run += e[i];
    PS[base + i] = run * inv;
    pAlphaT[base + i] = e[i] * inv;
  }
}

// ---------------------------------------------------------------------------
// scores[b,h,l,p] = (q.k/8) * Kterm + Bterm, written as f32 to d_out.
// Kterm/Bterm via 15 bucket sums S_r of pAlpha over m, computed from PS:
// bucket r covers |l-m| in [A_r,B_r]; contiguous intervals -> prefix diffs.
// One block: 16 l-rows x all h x all p. S computed once per (l,p), reused 8x.
// ---------------------------------------------------------------------------
__global__ __launch_bounds__(256)
void scores_kernel(const float* __restrict__ q, const float* __restrict__ kp,
                   const float* __restrict__ PS,
                   const float* __restrict__ embK, const float* __restrict__ embB,
                   float* __restrict__ sc_out)
{
  const int L = 2048, P = 64, H = 8, DK = 64, C = 512;
  __shared__ float qs[16][512];
  __shared__ float ks[64][68];
  __shared__ float eK[15][8], eB[15][8];
  const int b = blockIdx.y, l0 = blockIdx.x * 16;
  const int t = threadIdx.x;
  if (t < 120) { eK[t >> 3][t & 7] = embK[t]; eB[t >> 3][t & 7] = embB[t]; }
  const float* qb = q + ((size_t)b * L + l0) * C;
  for (int i = t; i < 2048; i += 256)               // 16x512 floats as float4
    ((float4*)&qs[0][0])[i] = ((const float4*)qb)[i];
  __syncthreads();
  const int p = t & 63, lw = t >> 6;                // lane = p, wave = l-group
  // upper distance bound per bucket (A_r = B_{r-1}+1)
  const int Btab[15] = {0,1,2,3,4,5,6,8,10,14,22,38,70,134,1<<20};
  float S[4][15];
  const float* ps = PS + ((size_t)b * P + p) * L;
#pragma unroll
  for (int il = 0; il < 4; ++il) {
    const int l = l0 + lw * 4 + il;
    float v[15], w[15];
#pragma unroll
    for (int r = 0; r < 15; ++r) {
      int hi = l + Btab[r]; if (hi > L - 1) hi = L - 1;
      v[r] = ps[hi];                                 // right-side prefix sample
      int lo = l - 1 - Btab[r];
      w[r] = (lo < 0) ? 0.f : ps[lo];                // left-side prefix sample
    }
    S[il][0] = v[0] - w[0];                          // d == 0 (count once)
#pragma unroll
    for (int r = 1; r < 15; ++r) S[il][r] = (v[r] - v[r-1]) + (w[r-1] - w[r]);
  }
  const float* kb = kp + (size_t)b * P * C;
  for (int h = 0; h < H; ++h) {
    __syncthreads();                                 // protect ks reuse
    {
      const int pr = t >> 2, dq = (t & 3) << 4;      // 64 rows x 64 d per h
      const float* src = kb + (size_t)pr * C + h * DK + dq;
#pragma unroll
      for (int qq = 0; qq < 4; ++qq)
        *(float4*)(&ks[pr][dq + qq * 4]) = *(const float4*)(src + qq * 4);
    }
    __syncthreads();
#pragma unroll
    for (int il = 0; il < 4; ++il) {
      const int lr = lw * 4 + il;
      float dot = 0.f;
#pragma unroll
      for (int d4 = 0; d4 < DK; d4 += 4) {
        float4 qv = *(const float4*)(&qs[lr][h * DK + d4]);
        float4 kv = *(const float4*)(&ks[p][d4]);
        dot += qv.x * kv.x + qv.y * kv.y + qv.z * kv.z + qv.w * kv.w;
      }
      float Kt = 0.f, Bt = 0.f;
#pragma unroll
      for (int r = 0; r < 15; ++r) { Kt += eK[r][h] * S[il][r]; Bt += eB[r][h] * S[il][r]; }
      const int l = l0 + lr;
      sc_out[(((size_t)b * H + h) * L + l) * P + p] = dot * 0.125f * Kt + Bt;
    }
  }
}

// ---------------------------------------------------------------------------
// softmax over P (per (b,h,l) row, one wave) + z_pre = alpha @ v  -> f32 ws
// ---------------------------------------------------------------------------
__global__ __launch_bounds__(256)
void softmax_pv(const float* __restrict__ sc, const float* __restrict__ vp,
                float* __restrict__ zpre)
{
  const int L = 2048, P = 64, H = 8, DK = 64, C = 512;
  __shared__ float vs[64][68];
  __shared__ float al[4][64];
  const int b = blockIdx.y, l0 = blockIdx.x * 4;
  const int t = threadIdx.x;
  const int lane = t & 63, lw = t >> 6;
  const float* vb = vp + (size_t)b * P * C;
  for (int h = 0; h < H; ++h) {
    __syncthreads();                                 // protect vs/al reuse
    {
      const int pr = t >> 2, dq = (t & 3) << 4;
      const float* src = vb + (size_t)pr * C + h * DK + dq;
#pragma unroll
      for (int qq = 0; qq < 4; ++qq)
        *(float4*)(&vs[pr][dq + qq * 4]) = *(const float4*)(src + qq * 4);
    }
    // softmax: wave lw handles row l0+lw, lanes = p
    float s = sc[(((size_t)b * H + h) * L + l0 + lw) * P + lane];
    float m = s;
#pragma unroll
    for (int o = 32; o > 0; o >>= 1) m = fmaxf(m, __shfl_xor(m, o, 64));
    float e = __expf(s - m);
    float T = e;
#pragma unroll
    for (int o = 32; o > 0; o >>= 1) T += __shfl_xor(T, o, 64);
    al[lw][lane] = e / T;
    __syncthreads();
    // PV: thread (lw, d=lane)
    float acc = 0.f;
#pragma unroll
    for (int pp = 0; pp < 64; ++pp) acc += al[lw][pp] * vs[pp][lane];
    zpre[((size_t)b * L + l0 + lw) * C + h * DK + lane] = acc;
  }
}

// ---------------------------------------------------------------------------
extern "C" void kernel_launch(void* const* d_in, const int* in_sizes, int n_in,
                              void* d_out, int out_size, void* d_ws, size_t ws_size,
                              hipStream_t stream)
{
  const int B = 8, L = 2048, C = 512, P = 64, H = 8, DK = 64;
  const float* qx   = (const float*)d_in[0];
  const float* kx   = (const float*)d_in[1];
  const float* vx   = (const float*)d_in[2];
  const int*  maskPAD = (const int*)d_in[3];
  const float* Wp = (const float*)d_in[4];
  const float* bp = (const float*)d_in[5];
  const float* Wq = (const float*)d_in[6];
  const float* bq = (const float*)d_in[7];
  const float* Wk = (const float*)d_in[8];
  const float* bk = (const float*)d_in[9];
  const float* Wv = (const float*)d_in[10];
  const float* bv = (const float*)d_in[11];
  const float* Wo = (const float*)d_in[12];
  const float* bo = (const float*)d_in[13];
  const float* embK = (const float*)d_in[14];
  const float* embB = (const float*)d_in[15];

  // f32 outputs, concatenated in return order
  float* z_out  = (float*)d_out;                          // [B,L,C]
  float* ps_out = z_out + (size_t)B * L * C;              // [B,L,P]
  float* sc_out = ps_out + (size_t)B * L * P;             // [B,H,L,P]

  // workspace (f32), aliased to stay under ~46 MB:
  float* ws = (float*)d_ws;
  float* pAlphaT = ws;                                    // B*P*L   (live: steps 2-3)
  float* PS      = pAlphaT + (size_t)B * P * L;           // B*P*L   (live: steps 2-5)
  float* pscF    = PS      + (size_t)B * P * L;           // B*L*P   (live: steps 1-2)
  // after step 2, pscF region is dead -> reuse for the 4 small [B,P,C] buffers
  float* kxc     = pscF;                                  // B*P*C = 262144
  float* vxc     = kxc + (size_t)B * P * C;
  float* kp      = vxc + (size_t)B * P * C;
  float* vp      = kp  + (size_t)B * P * C;               // ends exactly at pscF + B*L*P
  float* qbuf    = pscF + (size_t)B * L * P;              // B*L*C   (live: steps 4-5)
  float* zpre    = qbuf;                                  // aliases qbuf (live: steps 6-7)

  // 1) pScore = vx @ Wp + bp   [16384,512]x[512,64] -> f32 ws
  gemm_f32<<<dim3(1, (B * L) / 64, 1), 256, 0, stream>>>(
      vx, Wp, bp, pscF, B * L, P, C, 0, 0, 0);
  // 2) mask + softmax over L + prefix scan (also writes pScore output)
  softmax_scan<<<dim3(P, B), 256, 0, stream>>>(pscF, maskPAD, ps_out, pAlphaT, PS);
  // 3) kxc/vxc = pAlpha^T @ {kx,vx}  (batched [64,2048]x[2048,512])
  gemm_f32<<<dim3(C / 64, 1, B), 256, 0, stream>>>(
      pAlphaT, kx, nullptr, kxc, P, C, L, (long)P * L, (long)L * C, (long)P * C);
  gemm_f32<<<dim3(C / 64, 1, B), 256, 0, stream>>>(
      pAlphaT, vx, nullptr, vxc, P, C, L, (long)P * L, (long)L * C, (long)P * C);
  // 4) projections
  gemm_f32<<<dim3((H * DK) / 64, (B * L) / 64, 1), 256, 0, stream>>>(
      qx, Wq, bq, qbuf, B * L, H * DK, C, 0, 0, 0);
  gemm_f32<<<dim3((H * DK) / 64, (B * P) / 64, 1), 256, 0, stream>>>(
      kxc, Wk, bk, kp, B * P, H * DK, C, 0, 0, 0);
  gemm_f32<<<dim3((H * DK) / 64, (B * P) / 64, 1), 256, 0, stream>>>(
      vxc, Wv, bv, vp, B * P, H * DK, C, 0, 0, 0);
  // 5) scores (QK/8 * Kterm + Bterm) -> f32 output
  scores_kernel<<<dim3(L / 16, B), 256, 0, stream>>>(
      qbuf, kp, PS, embK, embB, sc_out);
  // 6) softmax over P + PV -> zpre (f32, reuses qbuf region after step 5)
  softmax_pv<<<dim3(L / 4, B), 256, 0, stream>>>(sc_out, vp, zpre);
  // 7) z = zpre @ Wo + bo -> f32 output
  gemm_f32<<<dim3(C / 64, (B * L) / 64, 1), 256, 0, stream>>>(
      zpre, Wo, bo, z_out, B * L, C, H * DK, 0, 0, 0);
}

// Round 3
// 342.805 us; speedup vs baseline: 2.2672x; 2.2672x over previous
//
#include <hip/hip_runtime.h>

// SelfAttention_Pseudoformer: B=8, L=2048, C=512, P=64, H=8, DK=64
// Outputs (f32, concat): z [B,L,C], pScore(masked) [B,L,P], scores [B,H,L,P]

typedef __attribute__((ext_vector_type(8))) short bhalf8;   // 8 bf16 (4 VGPR)
typedef __attribute__((ext_vector_type(4))) float fx4;      // MFMA acc frag

__device__ __forceinline__ unsigned short f2bf(float f) {
  union { float f; unsigned u; } v; v.f = f;
  unsigned u = v.u + 0x7fffu + ((v.u >> 16) & 1u);          // RNE
  return (unsigned short)(u >> 16);
}
__device__ __forceinline__ float bf2f(unsigned short h) {
  union { unsigned u; float f; } v; v.u = ((unsigned)h) << 16;
  return v.f;
}
__device__ __forceinline__ void gld16(const void* g, void* l) {
  __builtin_amdgcn_global_load_lds(
      (const __attribute__((address_space(1))) void*)g,
      (__attribute__((address_space(3))) void*)l, 16, 0, 0);
}

// ---------------------------------------------------------------------------
// bf16 MFMA GEMM:  C[r,c] = sum_k A[r,k] * BT[c,k]  (+bias[c])
// A, BT bf16; acc f32. 4 waves in 2x2. BK=32. Fragment-linear LDS staging via
// global_load_lds (per-lane global addr, wave-uniform LDS base -> conflict-free).
// CMODE: 0 = f32 out, 1 = bf16 out, 2 = bf16 vpT-scatter ( [b,h,d,p] from M=B*P,N=H*DK )
// Batched: z -> (b = z/HDIV, h = z%HDIV), offsets via sAb/sAh/sBb/sBh/sCb/sCh (elements).
// ---------------------------------------------------------------------------
template <int BM, int BN, int CMODE>
__global__ __launch_bounds__(256)
void gemm_mfma(const unsigned short* __restrict__ A, const unsigned short* __restrict__ BT,
               const float* __restrict__ bias, void* __restrict__ Cout,
               int K, int lda, int ldbt, int ldc, int HDIV,
               long sAb, long sAh, long sBb, long sBh, long sCb, long sCh)
{
  constexpr int NA = BM / 16, NB = BN / 16, NT = NA + NB;
  constexpr int WM = BM / 2, WN = BN / 2, FM = WM / 16, FN = WN / 16;
  __shared__ __align__(16) unsigned short lds[NT * 512];   // NT tiles x 1KB
  const int t = threadIdx.x, l = t & 63, w = t >> 6;
  const int wr = w >> 1, wc = w & 1;
  const int z = blockIdx.z, b = z / HDIV, h = z % HDIV;
  const int row0 = blockIdx.y * BM, col0 = blockIdx.x * BN;
  const unsigned short* Ag = A + b * sAb + h * sAh + (long)row0 * lda;
  const unsigned short* Bg = BT + b * sBb + h * sBh + (long)col0 * ldbt;
  const int lr = l & 15, lc = l >> 4;

  fx4 acc[FM][FN];
#pragma unroll
  for (int i = 0; i < FM; ++i)
#pragma unroll
    for (int j = 0; j < FN; ++j) acc[i][j] = fx4{0.f, 0.f, 0.f, 0.f};

  for (int k0 = 0; k0 < K; k0 += 32) {
#pragma unroll
    for (int i = 0; i < NT / 4; ++i) {                      // stage NT 16-row tiles
      const int tile = w + i * 4;
      const unsigned short* g;
      if (tile < NA) g = Ag + (long)(tile * 16 + lr) * lda + k0 + lc * 8;
      else           g = Bg + (long)((tile - NA) * 16 + lr) * ldbt + k0 + lc * 8;
      gld16(g, &lds[tile * 512]);
    }
    __syncthreads();
    bhalf8 af[FM], bf[FN];
#pragma unroll
    for (int i = 0; i < FM; ++i) af[i] = *(const bhalf8*)&lds[(wr * FM + i) * 512 + l * 8];
#pragma unroll
    for (int j = 0; j < FN; ++j) bf[j] = *(const bhalf8*)&lds[(NA + wc * FN + j) * 512 + l * 8];
#pragma unroll
    for (int i = 0; i < FM; ++i)
#pragma unroll
      for (int j = 0; j < FN; ++j)
        acc[i][j] = __builtin_amdgcn_mfma_f32_16x16x32_bf16(af[i], bf[j], acc[i][j], 0, 0, 0);
    __syncthreads();
  }

  // epilogue: acc elem jj -> row = row0+wr*WM+fm*16+lc*4+jj, col = col0+wc*WN+fn*16+lr
#pragma unroll
  for (int fm = 0; fm < FM; ++fm) {
#pragma unroll
    for (int fn = 0; fn < FN; ++fn) {
      const int rg0 = row0 + wr * WM + fm * 16 + lc * 4;
      const int cg = col0 + wc * WN + fn * 16 + lr;
      const float bb = bias ? bias[cg] : 0.f;
#pragma unroll
      for (int jj = 0; jj < 4; ++jj) {
        const int rg = rg0 + jj;
        const float v = acc[fm][fn][jj] + bb;
        if constexpr (CMODE == 0) {
          ((float*)Cout)[b * sCb + h * sCh + (long)rg * ldc + cg] = v;
        } else if constexpr (CMODE == 1) {
          ((unsigned short*)Cout)[b * sCb + h * sCh + (long)rg * ldc + cg] = f2bf(v);
        } else {                                            // vpT[b][h][d][p]
          ((unsigned short*)Cout)[(((long)(rg >> 6) * 8 + (cg >> 6)) * 64 + (cg & 63)) * 64 + (rg & 63)] = f2bf(v);
        }
      }
    }
  }
}

// ---------------------------------------------------------------------------
// f32 -> bf16 convert (flat, n4 float4s)
// ---------------------------------------------------------------------------
__global__ __launch_bounds__(256)
void cvt_bf16(const float* __restrict__ in, unsigned short* __restrict__ out, int n4)
{
  int i = blockIdx.x * 256 + threadIdx.x;
  if (i < n4) {
    float4 v = ((const float4*)in)[i];
    ushort4 o; o.x = f2bf(v.x); o.y = f2bf(v.y); o.z = f2bf(v.z); o.w = f2bf(v.w);
    ((ushort4*)out)[i] = o;
  }
}

// ---------------------------------------------------------------------------
// transpose + convert: in [batch][R][Cd] f32 -> out [batch][Cd][R] bf16
// grid (Cd/64, R/64, batch)
// ---------------------------------------------------------------------------
__global__ __launch_bounds__(256)
void tconv(const float* __restrict__ in, unsigned short* __restrict__ out,
           int R, int Cd, long sIn, long sOut)
{
  __shared__ float tile[64][65];
  in += (long)blockIdx.z * sIn; out += (long)blockIdx.z * sOut;
  const int r0 = blockIdx.y * 64, c0 = blockIdx.x * 64;
  const int t = threadIdx.x, tr = t >> 4, tc4 = (t & 15) * 4;
#pragma unroll
  for (int pass = 0; pass < 4; ++pass) {
    int r = pass * 16 + tr;
    float4 v = *(const float4*)(in + (long)(r0 + r) * Cd + c0 + tc4);
    tile[r][tc4] = v.x; tile[r][tc4 + 1] = v.y; tile[r][tc4 + 2] = v.z; tile[r][tc4 + 3] = v.w;
  }
  __syncthreads();
#pragma unroll
  for (int pass = 0; pass < 4; ++pass) {
    int c = pass * 16 + tr;
    ushort4 o;
    o.x = f2bf(tile[tc4][c]);     o.y = f2bf(tile[tc4 + 1][c]);
    o.z = f2bf(tile[tc4 + 2][c]); o.w = f2bf(tile[tc4 + 3][c]);
    *(ushort4*)(out + (long)(c0 + c) * R + r0 + tc4) = o;
  }
}

// ---------------------------------------------------------------------------
// mask + softmax over L per (b,p) + normalized inclusive prefix scan.
// writes masked pScore f32 (d_out), pAlphaT bf16 [B,P,L], PS f32 [B,P,L].
// ---------------------------------------------------------------------------
__global__ __launch_bounds__(256)
void softmax_scan(const float* __restrict__ pscF, const int* __restrict__ maskPAD,
                  float* __restrict__ ps_out,
                  unsigned short* __restrict__ pA_bf, float* __restrict__ PS)
{
  const int L = 2048, P = 64;
  __shared__ float red[256];
  const int p = blockIdx.x, b = blockIdx.y, t = threadIdx.x;
  const float* col = pscF + (size_t)b * L * P + p;
  float* ocol = ps_out + (size_t)b * L * P + p;
  const int* mrow = maskPAD + (size_t)b * L * L;            // maskPAD[b,0,:]
  float v[8]; float mx = -3.4e38f;
#pragma unroll
  for (int i = 0; i < 8; ++i) {
    int ll = t * 8 + i;
    float x = col[(size_t)ll * P];
    if (mrow[ll] == 0) x = -32768.0f;
    v[i] = x; mx = fmaxf(mx, x);
    ocol[(size_t)ll * P] = x;
  }
  red[t] = mx; __syncthreads();
  for (int s = 128; s > 0; s >>= 1) { if (t < s) red[t] = fmaxf(red[t], red[t + s]); __syncthreads(); }
  float m = red[0]; __syncthreads();
  float e[8]; float s = 0.f;
#pragma unroll
  for (int i = 0; i < 8; ++i) { e[i] = expf(v[i] - m); s += e[i]; }
  red[t] = s; __syncthreads();
  for (int o = 1; o < 256; o <<= 1) {
    float x = (t >= o) ? red[t - o] : 0.f;
    __syncthreads(); red[t] += x; __syncthreads();
  }
  float inv = 1.0f / red[255];
  float run = red[t] - s;
  size_t base = ((size_t)b * P + p) * L + (size_t)t * 8;
#pragma unroll
  for (int i = 0; i < 8; ++i) {
    run += e[i];
    PS[base + i] = run * inv;
    pA_bf[base + i] = f2bf(e[i] * inv);
  }
}

// ---------------------------------------------------------------------------
// scores epilogue + softmax over P, fused.
// sc = qk*0.125*Kterm + Bterm (f32 -> d_out); alpha = softmax_p(sc) bf16 in-place over qk.
// Kterm/Bterm from 15 rel-pos bucket sums S_r (prefix-sample diffs of PS).
// grid (L/16, B); wave lw owns rows l0+lw*4..+3, lane = p.
// ---------------------------------------------------------------------------
__global__ __launch_bounds__(256)
void epi_softmax(const unsigned short* __restrict__ qk, const float* __restrict__ PS,
                 const float* __restrict__ embK, const float* __restrict__ embB,
                 float* __restrict__ sc_out, unsigned short* __restrict__ alpha)
{
  const int L = 2048;
  __shared__ float eK[15][8], eB[15][8];
  const int b = blockIdx.y, l0 = blockIdx.x * 16, t = threadIdx.x;
  if (t < 120) { eK[t >> 3][t & 7] = embK[t]; eB[t >> 3][t & 7] = embB[t]; }
  __syncthreads();
  const int p = t & 63, lw = t >> 6;
  const int Btab[15] = {0,1,2,3,4,5,6,8,10,14,22,38,70,134,1<<20};
  float S[4][15];
  const float* ps = PS + ((size_t)b * 64 + p) * L;
#pragma unroll
  for (int il = 0; il < 4; ++il) {
    const int ll = l0 + lw * 4 + il;
    float v[15], w[15];
#pragma unroll
    for (int r = 0; r < 15; ++r) {
      int hi = ll + Btab[r]; if (hi > L - 1) hi = L - 1;
      v[r] = ps[hi];
      int lo = ll - 1 - Btab[r];
      w[r] = (lo < 0) ? 0.f : ps[lo];
    }
    S[il][0] = v[0] - w[0];
#pragma unroll
    for (int r = 1; r < 15; ++r) S[il][r] = (v[r] - v[r - 1]) + (w[r - 1] - w[r]);
  }
  for (int h = 0; h < 8; ++h) {
#pragma unroll
    for (int il = 0; il < 4; ++il) {
      float Kt = 0.f, Bt = 0.f;
#pragma unroll
      for (int r = 0; r < 15; ++r) { Kt += eK[r][h] * S[il][r]; Bt += eB[r][h] * S[il][r]; }
      const size_t idx = (((size_t)(b * 8 + h)) * L + (l0 + lw * 4 + il)) * 64 + p;
      float sv = bf2f(qk[idx]) * 0.125f * Kt + Bt;
      sc_out[idx] = sv;
      float mm = sv;
#pragma unroll
      for (int o = 32; o > 0; o >>= 1) mm = fmaxf(mm, __shfl_xor(mm, o, 64));
      float e = __expf(sv - mm);
      float T = e;
#pragma unroll
      for (int o = 32; o > 0; o >>= 1) T += __shfl_xor(T, o, 64);
      alpha[idx] = f2bf(e / T);
    }
  }
}

// ---------------------------------------------------------------------------
extern "C" void kernel_launch(void* const* d_in, const int* in_sizes, int n_in,
                              void* d_out, int out_size, void* d_ws, size_t ws_size,
                              hipStream_t stream)
{
  const int B = 8, L = 2048, C = 512, P = 64, H = 8, DK = 64;
  const float* qx = (const float*)d_in[0];
  const float* kx = (const float*)d_in[1];
  const float* vx = (const float*)d_in[2];
  const int* maskPAD = (const int*)d_in[3];
  const float* Wp = (const float*)d_in[4];
  const float* bp = (const float*)d_in[5];
  const float* Wq = (const float*)d_in[6];
  const float* bq = (const float*)d_in[7];
  const float* Wk = (const float*)d_in[8];
  const float* bk = (const float*)d_in[9];
  const float* Wv = (const float*)d_in[10];
  const float* bv = (const float*)d_in[11];
  const float* Wo = (const float*)d_in[12];
  const float* bo = (const float*)d_in[13];
  const float* embK = (const float*)d_in[14];
  const float* embB = (const float*)d_in[15];

  float* z_out  = (float*)d_out;                         // [B,L,C]
  float* ps_out = z_out + (size_t)B * L * C;             // [B,L,P]
  float* sc_out = ps_out + (size_t)B * L * P;            // [B,H,L,P]

  // workspace layout (bytes), total ~65.1 MB
  char* w8 = (char*)d_ws;
  size_t o = 0;
  auto take = [&](size_t n) { char* r = w8 + o; o += n; return r; };
  unsigned short* R_A  = (unsigned short*)take(16777216); // vx_bf -> qx_bf
  unsigned short* R_B  = (unsigned short*)take(16777216); // qbuf -> zpre
  unsigned short* R_C  = (unsigned short*)take(16777216); // kxT -> vxT -> qk/alpha
  unsigned short* WqT  = (unsigned short*)take(524288);
  unsigned short* WkT  = (unsigned short*)take(524288);
  unsigned short* WvT  = (unsigned short*)take(524288);
  unsigned short* WoT  = (unsigned short*)take(524288);
  unsigned short* WpT  = (unsigned short*)take(65536);
  float* pscF          = (float*)take(4194304);          // [B*L, P]
  float* PS            = (float*)take(4194304);          // [B,P,L]
  unsigned short* pAbf = (unsigned short*)take(2097152); // [B,P,L]
  unsigned short* kxc  = (unsigned short*)take(524288);  // [B*P, C]
  unsigned short* vxc  = (unsigned short*)take(524288);
  unsigned short* kp   = (unsigned short*)take(524288);  // [B,P,H*DK]
  unsigned short* vpT  = (unsigned short*)take(524288);  // [B,H,DK,P]

  const long LC = (long)L * C, PC = (long)P * C, LP = (long)L * P;

  // 1) weight transposes (f32 -> bf16, [K][N] -> [N][K])
  tconv<<<dim3(8, 8, 1), 256, 0, stream>>>(Wq, WqT, 512, 512, 0, 0);
  tconv<<<dim3(8, 8, 1), 256, 0, stream>>>(Wk, WkT, 512, 512, 0, 0);
  tconv<<<dim3(8, 8, 1), 256, 0, stream>>>(Wv, WvT, 512, 512, 0, 0);
  tconv<<<dim3(8, 8, 1), 256, 0, stream>>>(Wo, WoT, 512, 512, 0, 0);
  tconv<<<dim3(1, 8, 1), 256, 0, stream>>>(Wp, WpT, 512, 64, 0, 0);
  // 2) vx -> bf16
  cvt_bf16<<<dim3(8192), 256, 0, stream>>>(vx, R_A, B * L * C / 4);
  // 3) pScore = vx @ Wp + bp  (f32 out)
  gemm_mfma<64, 64, 0><<<dim3(1, 256, 1), 256, 0, stream>>>(
      R_A, WpT, bp, pscF, 512, 512, 512, 64, 1, 0, 0, 0, 0, 0, 0);
  // 4) mask + softmax_L + prefix scan
  softmax_scan<<<dim3(P, B), 256, 0, stream>>>(pscF, maskPAD, ps_out, pAbf, PS);
  // 5) qx -> bf16 (reuse R_A; vx_bf dead)
  cvt_bf16<<<dim3(8192), 256, 0, stream>>>(qx, R_A, B * L * C / 4);
  // 6) kx -> kxT bf16 [B,C,L]
  tconv<<<dim3(8, 32, 8), 256, 0, stream>>>(kx, R_C, L, C, LC, LC);
  // 7) kxc = pAlphaT @ kx  ([64,2048]x[2048,512] per b, bf16 out)
  gemm_mfma<64, 128, 1><<<dim3(4, 1, 8), 256, 0, stream>>>(
      pAbf, R_C, nullptr, kxc, 2048, 2048, 2048, 512, 1, LP, 0, LC, 0, PC, 0);
  // 8) vx -> vxT bf16 (reuse R_C)
  tconv<<<dim3(8, 32, 8), 256, 0, stream>>>(vx, R_C, L, C, LC, LC);
  // 9) vxc
  gemm_mfma<64, 128, 1><<<dim3(4, 1, 8), 256, 0, stream>>>(
      pAbf, R_C, nullptr, vxc, 2048, 2048, 2048, 512, 1, LP, 0, LC, 0, PC, 0);
  // 10) K-proj: kp = kxc @ Wk + bk (bf16, [B*P, 512])
  gemm_mfma<64, 128, 1><<<dim3(4, 8, 1), 256, 0, stream>>>(
      kxc, WkT, bk, kp, 512, 512, 512, 512, 1, 0, 0, 0, 0, 0, 0);
  // 11) V-proj -> vpT scatter [B,H,DK,P]
  gemm_mfma<64, 128, 2><<<dim3(4, 8, 1), 256, 0, stream>>>(
      vxc, WvT, bv, vpT, 512, 512, 512, 512, 1, 0, 0, 0, 0, 0, 0);
  // 12) Q-proj: qbuf = qx @ Wq + bq (bf16, [B*L, 512])
  gemm_mfma<128, 128, 1><<<dim3(4, 128, 1), 256, 0, stream>>>(
      R_A, WqT, bq, R_B, 512, 512, 512, 512, 1, 0, 0, 0, 0, 0, 0);
  // 13) qk[b,h,l,p] = q . k (bf16 out, batched over (b,h)); vxT dead -> R_C
  gemm_mfma<128, 64, 1><<<dim3(1, 16, 64), 256, 0, stream>>>(
      R_B, kp, nullptr, R_C, 64, 512, 512, 64, 8,
      LC, 64, PC, 64, 8L * L * 64, (long)L * 64);
  // 14) scores = qk/8*Kterm + Bterm (f32 -> d_out) + softmax_P -> alpha (in-place R_C)
  epi_softmax<<<dim3(L / 16, B), 256, 0, stream>>>(R_C, PS, embK, embB, sc_out, R_C);
  // 15) zpre = alpha @ v (bf16 [B,L,H*DK] into R_B; qbuf dead)
  gemm_mfma<128, 64, 1><<<dim3(1, 16, 64), 256, 0, stream>>>(
      R_C, vpT, nullptr, R_B, 64, 64, 64, 512, 8,
      8L * L * 64, (long)L * 64, 8L * 64 * 64, 64L * 64, LC, 64);
  // 16) z = zpre @ Wo + bo (f32 -> d_out)
  gemm_mfma<128, 128, 0><<<dim3(4, 128, 1), 256, 0, stream>>>(
      R_B, WoT, bo, z_out, 512, 512, 512, 512, 1, 0, 0, 0, 0, 0, 0);
}